// Round 7
// baseline (358.296 us; speedup 1.0000x reference)
//
#include <hip/hip_runtime.h>
#include <math.h>

// NoisyTopkRouter: B=8,S=4096,D=1024,E=64,k=2  (M=32768 tokens)
// R11: R10b + (1) coalesced B image [tile][wave][frag][lane*16B] -> every B load
//      is a contiguous 1KB wave-read; (2) B register double-buffer (named E/O
//      sets), B(t+1) issued at top of iter t -> full iteration of latency slack;
//      (3) waitcnt asm without "memory" clobber (SCHED0 brackets keep order) so
//      the compiler doesn't drain vmcnt at the barrier; (4) clock_probe kernel:
//      32768-deep dependent v_fma chain, 1 wave -- its rocprof dur_us measures
//      the effective shader clock (55us @2.4GHz, >=150us if throttled).
// Math order identical to R5-R10b -> bit-identical outputs (absmax 0.00390625).

#define DIM 1024
#define NEXP 64
#define CS 132
#define LOSCALE 2048.0f
#define INV_LOSCALE (1.0f / 2048.0f)
#define AROW 272              // bytes per A row in LDS (odd multiple of 16)
#define ABUF 8704             // 32 rows * 272

using half8v   = __attribute__((ext_vector_type(8)))  _Float16;
using floatx16 = __attribute__((ext_vector_type(16))) float;

#define MFMA32(a, b, c) __builtin_amdgcn_mfma_f32_32x32x16_f16((a), (b), (c), 0, 0, 0)

#define WAITLGKM0 asm volatile("s_waitcnt lgkmcnt(0)")
#define SCHED0    __builtin_amdgcn_sched_barrier(0)
#define BAR       __builtin_amdgcn_s_barrier()

// ---------------- clock probe: dependent FMA chain, 1 wave -------------------------
// 4096 iters x 8 dependent v_fma_f32 (~4cyc each) = 131072 cycles.
// rocprof dur_us: ~55us @2.4GHz, ~187us @700MHz. Readout only; result kept live
// via an opaque store into workspace.
__global__ __launch_bounds__(64)
void clock_probe(float* __restrict__ ws)
{
    float x = (float)(threadIdx.x + 1) * 1e-6f;
#pragma unroll 1
    for (int i = 0; i < 4096; ++i) {
        x = fmaf(x, 1.0000001f, 1.0f);
        x = fmaf(x, 1.0000001f, 1.0f);
        x = fmaf(x, 1.0000001f, 1.0f);
        x = fmaf(x, 1.0000001f, 1.0f);
        x = fmaf(x, 1.0000001f, 1.0f);
        x = fmaf(x, 1.0000001f, 1.0f);
        x = fmaf(x, 1.0000001f, 1.0f);
        x = fmaf(x, 1.0000001f, 1.0f);
    }
    if (x == 12345.678f) ws[threadIdx.x] = x;   // never true; keeps chain live
}

// ---------------- prep: split weights into coalesced fragment image ----------------
// Image: [t=0..15][w=0..3][frag f=0..7][lane=0..63][8 halves]
//   f = ss*2 + (lo?1:0), ss=0..3 sub-step of the 64-K tile; lane = oct*32+row31.
// Reader wave w, lane l: frag f at Bp + ((t*4+w)*8+f)*512 + l*8   (halves)
__global__ __launch_bounds__(512)
void prep_B(const float* __restrict__ Wl, const float* __restrict__ Wn,
            _Float16* __restrict__ Bp)
{
    const int idx = blockIdx.x * 512 + threadIdx.x;   // 16384 threads
    const int r  = idx >> 7;        // 0..127 (0..63 = Wl cols, 64..127 = Wn cols)
    const int c2 = idx & 127;       // 8-float chunk across K=1024
    const float* W = (r < 64) ? (Wl + (size_t)r * DIM) : (Wn + (size_t)(r - 64) * DIM);
    float f[8];
    *(float4*)(f)     = *(const float4*)(W + c2 * 8);
    *(float4*)(f + 4) = *(const float4*)(W + c2 * 8 + 4);
    half8v hi, lo;
#pragma unroll
    for (int i = 0; i < 8; i++) {
        _Float16 hh = (_Float16)f[i];
        hi[i] = hh;
        lo[i] = (_Float16)((f[i] - (float)hh) * LOSCALE);
    }
    const int tau = c2 >> 1, hf = c2 & 1;    // global 16-K tile, oct half
    const int t = tau >> 2, ss = tau & 3;    // 64-K tile, sub-step
    const int w = r >> 5;                    // wave / column group
    const int lane = hf * 32 + (r & 31);
    _Float16* base = Bp + (((size_t)(t * 4 + w) * 8 + ss * 2) * 64 + lane) * 8;
    *(half8v*)(base)       = hi;             // frag ss*2
    *(half8v*)(base + 512) = lo;             // frag ss*2+1
}

// ---------------- main fused kernel ------------------------------------------------
__global__ __launch_bounds__(256, 4)
void router_fused(const float* __restrict__ h, const _Float16* __restrict__ Bp,
                  const float* __restrict__ bl, const float* __restrict__ bn,
                  const float* __restrict__ noise,
                  float* __restrict__ outR, float* __restrict__ outIx,
                  float* __restrict__ outF)
{
    __shared__ __align__(16) char lds_raw[2 * ABUF];   // 17408 B; Cs needs 16896

    const int tid   = threadIdx.x;           // 0..255
    const int wv    = tid >> 6;              // 0..3  (column group)
    const int lane  = tid & 63;
    const int row31 = lane & 31;
    const int oct   = lane >> 5;
    const int colb  = wv * 32;               // 0,32,64,96
    const int tok0  = blockIdx.x * 32;

    // ---- A staging map: thread -> row rSt, 8-float group f8 of the 64-K tile ----
    const int rSt = tid >> 3, f8 = tid & 7;
    const float* aStage = h + (size_t)(tok0 + rSt) * DIM + f8 * 8;
    const int aWhi = rSt * AROW + f8 * 16;   // hi chunk byte offset; lo at +128

    // ---- B coalesced read base: frag f at +f*512 halves, 1KB contiguous/wave ----
    const _Float16* bBase = Bp + ((size_t)wv << 12) + (lane << 3);
    // tile t: + t*4*4096 halves

    // ---- A fragment read base ----
    const int rdHi = row31 * AROW;           // + (ss*2+oct)*16, lo +128

    floatx16 acc1, acc2;
#pragma unroll
    for (int i = 0; i < 16; i++) { acc1[i] = 0.f; acc2[i] = 0.f; }

#define LOADA(t, A0, A1) do {                                                  \
        (A0) = *(const float4*)(aStage + (t) * 64);                            \
        (A1) = *(const float4*)(aStage + (t) * 64 + 4);                        \
    } while (0)

#define SPLITW(bufc, A0, A1) do {                                              \
        float f_[8] = {(A0).x, (A0).y, (A0).z, (A0).w,                         \
                       (A1).x, (A1).y, (A1).z, (A1).w};                        \
        half8v hi_, lo_;                                                       \
        _Pragma("unroll")                                                      \
        for (int i_ = 0; i_ < 8; i_++) {                                       \
            _Float16 hh_ = (_Float16)f_[i_];                                   \
            hi_[i_] = hh_;                                                     \
            lo_[i_] = (_Float16)((f_[i_] - (float)hh_) * LOSCALE);             \
        }                                                                      \
        *(half8v*)((bufc) + aWhi)       = hi_;                                 \
        *(half8v*)((bufc) + aWhi + 128) = lo_;                                 \
    } while (0)

#define ISSUE_B(t, B0, B1, B2, B3, B4, B5, B6, B7) do {                        \
        const _Float16* bW_ = bBase + ((size_t)(t) << 14);                     \
        (B0) = *(const half8v*)(bW_);                                          \
        (B1) = *(const half8v*)(bW_ + 512);                                    \
        (B2) = *(const half8v*)(bW_ + 1024);                                   \
        (B3) = *(const half8v*)(bW_ + 1536);                                   \
        (B4) = *(const half8v*)(bW_ + 2048);                                   \
        (B5) = *(const half8v*)(bW_ + 2560);                                   \
        (B6) = *(const half8v*)(bW_ + 3072);                                   \
        (B7) = *(const half8v*)(bW_ + 3584);                                   \
    } while (0)

#define SUBSTEP(bufc, ss, BH, BL) do {                                         \
        const int co_ = ((ss) * 2 + oct) << 4;                                 \
        const half8v aH_ = *(const half8v*)((bufc) + rdHi + co_);              \
        const half8v aL_ = *(const half8v*)((bufc) + rdHi + co_ + 128);        \
        acc1 = MFMA32(aH_, (BH), acc1);                                        \
        acc2 = MFMA32(aH_, (BL), acc2);                                        \
        acc2 = MFMA32(aL_, (BH), acc2);                                        \
    } while (0)

#define COMPUTE(bufc, B0, B1, B2, B3, B4, B5, B6, B7) do {                     \
        SUBSTEP(bufc, 0, B0, B1);                                              \
        SUBSTEP(bufc, 1, B2, B3);                                              \
        SUBSTEP(bufc, 2, B4, B5);                                              \
        SUBSTEP(bufc, 3, B6, B7);                                              \
    } while (0)

    half8v eB0, eB1, eB2, eB3, eB4, eB5, eB6, eB7;   // B set for even tiles
    half8v oB0, oB1, oB2, oB3, oB4, oB5, oB6, oB7;   // B set for odd tiles
    char* const buf0 = lds_raw;
    char* const buf1 = lds_raw + ABUF;
    float4 aE0, aE1, aO0, aO1;

    // ---- prologue: B(0)->E set; tile0 -> buf0; tile1 -> O regs ----
    ISSUE_B(0, eB0, eB1, eB2, eB3, eB4, eB5, eB6, eB7);
    LOADA(0, aE0, aE1);
    SPLITW(buf0, aE0, aE1);
    LOADA(1, aO0, aO1);
    SCHED0; WAITLGKM0; SCHED0;
    BAR; SCHED0;

// iter t: issue B(t+1) -> opposite set; split/write A(t+1); load A(t+2);
//         compute tile t (B loaded one full iteration ago); lgkm-drain; barrier.
#define BODY(t, CBUF, NBUF, NB0,NB1,NB2,NB3,NB4,NB5,NB6,NB7,                   \
             CB0,CB1,CB2,CB3,CB4,CB5,CB6,CB7, AW0, AW1, AL0, AL1) do {         \
        ISSUE_B((t) + 1, NB0,NB1,NB2,NB3,NB4,NB5,NB6,NB7);                     \
        SPLITW(NBUF, AW0, AW1);                                                \
        LOADA((t) + 2, AL0, AL1);                                              \
        COMPUTE(CBUF, CB0,CB1,CB2,CB3,CB4,CB5,CB6,CB7);                        \
        SCHED0; WAITLGKM0; SCHED0;                                             \
        BAR; SCHED0;                                                           \
    } while (0)

    // t = 0..13 in parity pairs. Tile t: buf[t&1], B set [t&1] (E=even, O=odd).
    for (int tb = 0; tb < 7; ++tb) {
        const int t0 = 2 * tb;
        BODY(t0,     buf0, buf1,
             oB0,oB1,oB2,oB3,oB4,oB5,oB6,oB7,
             eB0,eB1,eB2,eB3,eB4,eB5,eB6,eB7, aO0, aO1, aE0, aE1);
        BODY(t0 + 1, buf1, buf0,
             eB0,eB1,eB2,eB3,eB4,eB5,eB6,eB7,
             oB0,oB1,oB2,oB3,oB4,oB5,oB6,oB7, aE0, aE1, aO0, aO1);
    }
    // t = 14 (even): B(15)->O set; write tile15 (O regs) -> buf1; no more A loads
    ISSUE_B(15, oB0, oB1, oB2, oB3, oB4, oB5, oB6, oB7);
    SPLITW(buf1, aO0, aO1);
    COMPUTE(buf0, eB0, eB1, eB2, eB3, eB4, eB5, eB6, eB7);
    SCHED0; WAITLGKM0; SCHED0;
    BAR; SCHED0;
    // t = 15: compute only
    COMPUTE(buf1, oB0, oB1, oB2, oB3, oB4, oB5, oB6, oB7);
    __syncthreads();                          // full drain before Cs overlay

#undef BODY
#undef COMPUTE
#undef SUBSTEP
#undef ISSUE_B
#undef SPLITW
#undef LOADA

    // ---- Cs: C layout col=lane&31, row=(reg&3)+8*(reg>>2)+4*oct (verified) ----
    float* Cs = (float*)lds_raw;
#pragma unroll
    for (int i = 0; i < 16; i++) {
        const int rowt = (i & 3) + 8 * (i >> 2) + 4 * oct;
        Cs[rowt * CS + colb + row31] = acc1[i] + acc2[i] * INV_LOSCALE;
    }
    __syncthreads();

    // ---- fused epilogue: lane = expert; 8 tokens per wave (verified R1-R10) ----
    const float blv = bl[lane];
    const float bnv = bn[lane];

    for (int t = wv; t < 32; t += 4) {
        const int gt = tok0 + t;
        float xr = Cs[t * CS + lane] + blv;
        float xf = Cs[t * CS + 64 + lane] + bnv;
        float nz = noise[(size_t)gt * NEXP + lane];

        // softplus (matches jax.nn.softplus)
        float stdv = fmaxf(xf, 0.f) + log1pf(expf(-fabsf(xf)));
        float noisy = fmaf(nz, stdv, xr);

        // merged max + argmax#1 (ties -> lowest index, matching lax.top_k)
        float v = noisy; int idx = lane;
#pragma unroll
        for (int o = 32; o > 0; o >>= 1) {
            float ov = __shfl_xor(v, o, 64);
            int   oi = __shfl_xor(idx, o, 64);
            if (ov > v || (ov == v && oi < idx)) { v = ov; idx = oi; }
        }
        const float v1 = v; const int i1 = idx;

        // full softmax over 64 lanes (max == v1)
        float p = expf(noisy - v1);
        float s = p;
#pragma unroll
        for (int o = 32; o > 0; o >>= 1) s += __shfl_xor(s, o, 64);
        float fullp = p / s;

        // argmax #2
        v = (lane == i1) ? -INFINITY : noisy; idx = lane;
#pragma unroll
        for (int o = 32; o > 0; o >>= 1) {
            float ov = __shfl_xor(v, o, 64);
            int   oi = __shfl_xor(idx, o, 64);
            if (ov > v || (ov == v && oi < idx)) { v = ov; idx = oi; }
        }
        const float v2 = v; const int i2 = idx;

        // sparse softmax over {i1,i2}
        float e2 = expf(v2 - v1);
        float den = 1.f + e2;
        float routep = (lane == i1) ? (1.f / den) : ((lane == i2) ? (e2 / den) : 0.f);

        outR[(size_t)gt * NEXP + lane] = routep;
        outF[(size_t)gt * NEXP + lane] = fullp;
        if (lane == 0) {
            outIx[(size_t)gt * 2 + 0] = (float)i1;
            outIx[(size_t)gt * 2 + 1] = (float)i2;
        }
    }
}

extern "C" void kernel_launch(void* const* d_in, const int* in_sizes, int n_in,
                              void* d_out, int out_size, void* d_ws, size_t ws_size,
                              hipStream_t stream) {
    const float* h     = (const float*)d_in[0];
    const float* Wl    = (const float*)d_in[1];
    const float* bl    = (const float*)d_in[2];
    const float* Wn    = (const float*)d_in[3];
    const float* bn    = (const float*)d_in[4];
    const float* noise = (const float*)d_in[5];
    float* out = (float*)d_out;

    const int M = in_sizes[0] / DIM;                 // 32768
    float* outR  = out;                              // [M,64]
    float* outIx = out + (size_t)M * NEXP;           // [M,2]
    float* outF  = outIx + (size_t)M * 2;            // [M,64]

    _Float16* Bp = (_Float16*)d_ws;                  // 512 KiB fragment image
    float* probe_ws = (float*)((char*)d_ws + (1 << 20));

    prep_B<<<32, 512, 0, stream>>>(Wl, Wn, Bp);
    router_fused<<<M / 32, 256, 0, stream>>>(h, Bp, bl, bn, noise, outR, outIx, outF);
    clock_probe<<<1, 64, 0, stream>>>(probe_ws);
}

// Round 8
// 253.618 us; speedup vs baseline: 1.4127x; 1.4127x over previous
//
#include <hip/hip_runtime.h>
#include <math.h>

// NoisyTopkRouter: B=8,S=4096,D=1024,E=64,k=2  (M=32768 tokens)
// R12: R11 minus clock_probe (it measured eff. clock ~1.0-1.2 GHz and cost 137us
//      of bench time), plus T5 s_setprio(1) around the MFMA cluster (4 independent
//      blocks/CU = the regime where setprio pays, m191).
//  - Block = 32 tok x 128 col, 256 thr = 4 waves; 1024 blocks = 4 indep blocks/CU.
//  - A staged in LDS (272B rows, conflict-free), split fp32->fp16 hi/lo once.
//  - B: coalesced fragment image [tile][wave][frag][lane*16B] (1KB contiguous
//    wave-reads), register double-buffered with named E/O sets, issued one full
//    iteration ahead.
//  - Math order identical to R5-R11 -> bit-identical outputs (absmax 0.00390625).

#define DIM 1024
#define NEXP 64
#define CS 132
#define LOSCALE 2048.0f
#define INV_LOSCALE (1.0f / 2048.0f)
#define AROW 272              // bytes per A row in LDS (odd multiple of 16)
#define ABUF 8704             // 32 rows * 272

using half8v   = __attribute__((ext_vector_type(8)))  _Float16;
using floatx16 = __attribute__((ext_vector_type(16))) float;

#define MFMA32(a, b, c) __builtin_amdgcn_mfma_f32_32x32x16_f16((a), (b), (c), 0, 0, 0)

#define WAITLGKM0 asm volatile("s_waitcnt lgkmcnt(0)")
#define SCHED0    __builtin_amdgcn_sched_barrier(0)
#define BAR       __builtin_amdgcn_s_barrier()

// ---------------- prep: split weights into coalesced fragment image ----------------
// Image: [t=0..15][w=0..3][frag f=0..7][lane=0..63][8 halves]
//   f = ss*2 + (lo?1:0), ss=0..3 sub-step of the 64-K tile; lane = oct*32+row31.
// Reader wave w, lane l: frag f at Bp + ((t*4+w)*8+f)*512 + l*8   (halves)
__global__ __launch_bounds__(512)
void prep_B(const float* __restrict__ Wl, const float* __restrict__ Wn,
            _Float16* __restrict__ Bp)
{
    const int idx = blockIdx.x * 512 + threadIdx.x;   // 16384 threads
    const int r  = idx >> 7;        // 0..127 (0..63 = Wl cols, 64..127 = Wn cols)
    const int c2 = idx & 127;       // 8-float chunk across K=1024
    const float* W = (r < 64) ? (Wl + (size_t)r * DIM) : (Wn + (size_t)(r - 64) * DIM);
    float f[8];
    *(float4*)(f)     = *(const float4*)(W + c2 * 8);
    *(float4*)(f + 4) = *(const float4*)(W + c2 * 8 + 4);
    half8v hi, lo;
#pragma unroll
    for (int i = 0; i < 8; i++) {
        _Float16 hh = (_Float16)f[i];
        hi[i] = hh;
        lo[i] = (_Float16)((f[i] - (float)hh) * LOSCALE);
    }
    const int tau = c2 >> 1, hf = c2 & 1;    // global 16-K tile, oct half
    const int t = tau >> 2, ss = tau & 3;    // 64-K tile, sub-step
    const int w = r >> 5;                    // wave / column group
    const int lane = hf * 32 + (r & 31);
    _Float16* base = Bp + (((size_t)(t * 4 + w) * 8 + ss * 2) * 64 + lane) * 8;
    *(half8v*)(base)       = hi;             // frag ss*2
    *(half8v*)(base + 512) = lo;             // frag ss*2+1
}

// ---------------- main fused kernel ------------------------------------------------
__global__ __launch_bounds__(256, 4)
void router_fused(const float* __restrict__ h, const _Float16* __restrict__ Bp,
                  const float* __restrict__ bl, const float* __restrict__ bn,
                  const float* __restrict__ noise,
                  float* __restrict__ outR, float* __restrict__ outIx,
                  float* __restrict__ outF)
{
    __shared__ __align__(16) char lds_raw[2 * ABUF];   // 17408 B; Cs needs 16896

    const int tid   = threadIdx.x;           // 0..255
    const int wv    = tid >> 6;              // 0..3  (column group)
    const int lane  = tid & 63;
    const int row31 = lane & 31;
    const int oct   = lane >> 5;
    const int colb  = wv * 32;               // 0,32,64,96
    const int tok0  = blockIdx.x * 32;

    // ---- A staging map: thread -> row rSt, 8-float group f8 of the 64-K tile ----
    const int rSt = tid >> 3, f8 = tid & 7;
    const float* aStage = h + (size_t)(tok0 + rSt) * DIM + f8 * 8;
    const int aWhi = rSt * AROW + f8 * 16;   // hi chunk byte offset; lo at +128

    // ---- B coalesced read base: frag f at +f*512 halves, 1KB contiguous/wave ----
    const _Float16* bBase = Bp + ((size_t)wv << 12) + (lane << 3);
    // tile t: + t*4*4096 halves

    // ---- A fragment read base ----
    const int rdHi = row31 * AROW;           // + (ss*2+oct)*16, lo +128

    floatx16 acc1, acc2;
#pragma unroll
    for (int i = 0; i < 16; i++) { acc1[i] = 0.f; acc2[i] = 0.f; }

#define LOADA(t, A0, A1) do {                                                  \
        (A0) = *(const float4*)(aStage + (t) * 64);                            \
        (A1) = *(const float4*)(aStage + (t) * 64 + 4);                        \
    } while (0)

#define SPLITW(bufc, A0, A1) do {                                              \
        float f_[8] = {(A0).x, (A0).y, (A0).z, (A0).w,                         \
                       (A1).x, (A1).y, (A1).z, (A1).w};                        \
        half8v hi_, lo_;                                                       \
        _Pragma("unroll")                                                      \
        for (int i_ = 0; i_ < 8; i_++) {                                       \
            _Float16 hh_ = (_Float16)f_[i_];                                   \
            hi_[i_] = hh_;                                                     \
            lo_[i_] = (_Float16)((f_[i_] - (float)hh_) * LOSCALE);             \
        }                                                                      \
        *(half8v*)((bufc) + aWhi)       = hi_;                                 \
        *(half8v*)((bufc) + aWhi + 128) = lo_;                                 \
    } while (0)

#define ISSUE_B(t, B0, B1, B2, B3, B4, B5, B6, B7) do {                        \
        const _Float16* bW_ = bBase + ((size_t)(t) << 14);                     \
        (B0) = *(const half8v*)(bW_);                                          \
        (B1) = *(const half8v*)(bW_ + 512);                                    \
        (B2) = *(const half8v*)(bW_ + 1024);                                   \
        (B3) = *(const half8v*)(bW_ + 1536);                                   \
        (B4) = *(const half8v*)(bW_ + 2048);                                   \
        (B5) = *(const half8v*)(bW_ + 2560);                                   \
        (B6) = *(const half8v*)(bW_ + 3072);                                   \
        (B7) = *(const half8v*)(bW_ + 3584);                                   \
    } while (0)

#define SUBSTEP(bufc, ss, BH, BL) do {                                         \
        const int co_ = ((ss) * 2 + oct) << 4;                                 \
        const half8v aH_ = *(const half8v*)((bufc) + rdHi + co_);              \
        const half8v aL_ = *(const half8v*)((bufc) + rdHi + co_ + 128);        \
        acc1 = MFMA32(aH_, (BH), acc1);                                        \
        acc2 = MFMA32(aH_, (BL), acc2);                                        \
        acc2 = MFMA32(aL_, (BH), acc2);                                        \
    } while (0)

#define COMPUTE(bufc, B0, B1, B2, B3, B4, B5, B6, B7) do {                     \
        __builtin_amdgcn_s_setprio(1);                                         \
        SUBSTEP(bufc, 0, B0, B1);                                              \
        SUBSTEP(bufc, 1, B2, B3);                                              \
        SUBSTEP(bufc, 2, B4, B5);                                              \
        SUBSTEP(bufc, 3, B6, B7);                                              \
        __builtin_amdgcn_s_setprio(0);                                         \
    } while (0)

    half8v eB0, eB1, eB2, eB3, eB4, eB5, eB6, eB7;   // B set for even tiles
    half8v oB0, oB1, oB2, oB3, oB4, oB5, oB6, oB7;   // B set for odd tiles
    char* const buf0 = lds_raw;
    char* const buf1 = lds_raw + ABUF;
    float4 aE0, aE1, aO0, aO1;

    // ---- prologue: B(0)->E set; tile0 -> buf0; tile1 -> O regs ----
    ISSUE_B(0, eB0, eB1, eB2, eB3, eB4, eB5, eB6, eB7);
    LOADA(0, aE0, aE1);
    SPLITW(buf0, aE0, aE1);
    LOADA(1, aO0, aO1);
    SCHED0; WAITLGKM0; SCHED0;
    BAR; SCHED0;

// iter t: issue B(t+1) -> opposite set; split/write A(t+1); load A(t+2);
//         compute tile t (B loaded one full iteration ago); lgkm-drain; barrier.
#define BODY(t, CBUF, NBUF, NB0,NB1,NB2,NB3,NB4,NB5,NB6,NB7,                   \
             CB0,CB1,CB2,CB3,CB4,CB5,CB6,CB7, AW0, AW1, AL0, AL1) do {         \
        ISSUE_B((t) + 1, NB0,NB1,NB2,NB3,NB4,NB5,NB6,NB7);                     \
        SPLITW(NBUF, AW0, AW1);                                                \
        LOADA((t) + 2, AL0, AL1);                                              \
        COMPUTE(CBUF, CB0,CB1,CB2,CB3,CB4,CB5,CB6,CB7);                        \
        SCHED0; WAITLGKM0; SCHED0;                                             \
        BAR; SCHED0;                                                           \
    } while (0)

    // t = 0..13 in parity pairs. Tile t: buf[t&1], B set [t&1] (E=even, O=odd).
    for (int tb = 0; tb < 7; ++tb) {
        const int t0 = 2 * tb;
        BODY(t0,     buf0, buf1,
             oB0,oB1,oB2,oB3,oB4,oB5,oB6,oB7,
             eB0,eB1,eB2,eB3,eB4,eB5,eB6,eB7, aO0, aO1, aE0, aE1);
        BODY(t0 + 1, buf1, buf0,
             eB0,eB1,eB2,eB3,eB4,eB5,eB6,eB7,
             oB0,oB1,oB2,oB3,oB4,oB5,oB6,oB7, aE0, aE1, aO0, aO1);
    }
    // t = 14 (even): B(15)->O set; write tile15 (O regs) -> buf1; no more A loads
    ISSUE_B(15, oB0, oB1, oB2, oB3, oB4, oB5, oB6, oB7);
    SPLITW(buf1, aO0, aO1);
    COMPUTE(buf0, eB0, eB1, eB2, eB3, eB4, eB5, eB6, eB7);
    SCHED0; WAITLGKM0; SCHED0;
    BAR; SCHED0;
    // t = 15: compute only
    COMPUTE(buf1, oB0, oB1, oB2, oB3, oB4, oB5, oB6, oB7);
    __syncthreads();                          // full drain before Cs overlay

#undef BODY
#undef COMPUTE
#undef SUBSTEP
#undef ISSUE_B
#undef SPLITW
#undef LOADA

    // ---- Cs: C layout col=lane&31, row=(reg&3)+8*(reg>>2)+4*oct (verified) ----
    float* Cs = (float*)lds_raw;
#pragma unroll
    for (int i = 0; i < 16; i++) {
        const int rowt = (i & 3) + 8 * (i >> 2) + 4 * oct;
        Cs[rowt * CS + colb + row31] = acc1[i] + acc2[i] * INV_LOSCALE;
    }
    __syncthreads();

    // ---- fused epilogue: lane = expert; 8 tokens per wave (verified R1-R11) ----
    const float blv = bl[lane];
    const float bnv = bn[lane];

    for (int t = wv; t < 32; t += 4) {
        const int gt = tok0 + t;
        float xr = Cs[t * CS + lane] + blv;
        float xf = Cs[t * CS + 64 + lane] + bnv;
        float nz = noise[(size_t)gt * NEXP + lane];

        // softplus (matches jax.nn.softplus)
        float stdv = fmaxf(xf, 0.f) + log1pf(expf(-fabsf(xf)));
        float noisy = fmaf(nz, stdv, xr);

        // merged max + argmax#1 (ties -> lowest index, matching lax.top_k)
        float v = noisy; int idx = lane;
#pragma unroll
        for (int o = 32; o > 0; o >>= 1) {
            float ov = __shfl_xor(v, o, 64);
            int   oi = __shfl_xor(idx, o, 64);
            if (ov > v || (ov == v && oi < idx)) { v = ov; idx = oi; }
        }
        const float v1 = v; const int i1 = idx;

        // full softmax over 64 lanes (max == v1)
        float p = expf(noisy - v1);
        float s = p;
#pragma unroll
        for (int o = 32; o > 0; o >>= 1) s += __shfl_xor(s, o, 64);
        float fullp = p / s;

        // argmax #2
        v = (lane == i1) ? -INFINITY : noisy; idx = lane;
#pragma unroll
        for (int o = 32; o > 0; o >>= 1) {
            float ov = __shfl_xor(v, o, 64);
            int   oi = __shfl_xor(idx, o, 64);
            if (ov > v || (ov == v && oi < idx)) { v = ov; idx = oi; }
        }
        const float v2 = v; const int i2 = idx;

        // sparse softmax over {i1,i2}
        float e2 = expf(v2 - v1);
        float den = 1.f + e2;
        float routep = (lane == i1) ? (1.f / den) : ((lane == i2) ? (e2 / den) : 0.f);

        outR[(size_t)gt * NEXP + lane] = routep;
        outF[(size_t)gt * NEXP + lane] = fullp;
        if (lane == 0) {
            outIx[(size_t)gt * 2 + 0] = (float)i1;
            outIx[(size_t)gt * 2 + 1] = (float)i2;
        }
    }
}

extern "C" void kernel_launch(void* const* d_in, const int* in_sizes, int n_in,
                              void* d_out, int out_size, void* d_ws, size_t ws_size,
                              hipStream_t stream) {
    const float* h     = (const float*)d_in[0];
    const float* Wl    = (const float*)d_in[1];
    const float* bl    = (const float*)d_in[2];
    const float* Wn    = (const float*)d_in[3];
    const float* bn    = (const float*)d_in[4];
    const float* noise = (const float*)d_in[5];
    float* out = (float*)d_out;

    const int M = in_sizes[0] / DIM;                 // 32768
    float* outR  = out;                              // [M,64]
    float* outIx = out + (size_t)M * NEXP;           // [M,2]
    float* outF  = outIx + (size_t)M * 2;            // [M,64]

    _Float16* Bp = (_Float16*)d_ws;                  // 512 KiB fragment image

    prep_B<<<32, 512, 0, stream>>>(Wl, Wn, Bp);
    router_fused<<<M / 32, 256, 0, stream>>>(h, Bp, bl, bn, noise, outR, outIx, outF);
}